// Round 6
// baseline (210.156 us; speedup 1.0000x reference)
//
#include <hip/hip_runtime.h>

#define BB 4
#define AA 100000
#define MM 32
#define NC 80
#define GX 391                 // ceil(AA/256)
#define NBLK (GX * BB)         // 1564 code blocks
#define FB 3125                // focal blocks
#define FT (FB * 256)          // 800,000 focal threads
#define N4 (BB * AA * (NC/4))  // 8,000,000 float4s == 10 * FT exactly
#define LN2 0.69314718055994530942f

// ws layout:
//   reg_part: float[NBLK]      @ byte 0
//   pos_part: uint[NBLK]       @ byte NBLK*4
//   cls_part: float[FB]        @ byte 2*NBLK*4      (ends ~25 KB)
//   codes:    schar[BB*AA]     @ byte 65536
// Everything written unconditionally each call -> no zero-init, no atomics.

__device__ __forceinline__ float hw_log2(float x) {
#if defined(__has_builtin)
#if __has_builtin(__builtin_amdgcn_logf)
    return __builtin_amdgcn_logf(x);   // raw v_log_f32 (log2), 1 instr
#else
    return __log2f(x);
#endif
#else
    return __log2f(x);
#endif
}

__global__ __launch_bounds__(256) void codes_kernel(
    const float* __restrict__ anchors,      // AA*4
    const float* __restrict__ annotations,  // BB*MM*5
    const float* __restrict__ regression,   // BB*AA*4
    float* __restrict__ reg_part,
    unsigned* __restrict__ pos_part,
    signed char* __restrict__ codes)
{
    __shared__ float ann[MM * 5];
    const int b = blockIdx.y;
    const int tid = threadIdx.x;
    if (tid < MM * 5) ann[tid] = annotations[b * MM * 5 + tid];
    __syncthreads();

    const int a = blockIdx.x * 256 + tid;
    float reg_sum = 0.0f;
    int pos_cnt = 0;

    if (a < AA) {
        const float4 an = ((const float4*)anchors)[a];
        const float ax1 = an.x, ay1 = an.y, ax2 = an.z, ay2 = an.w;
        // exact IEEE ops (no FMA contraction) so pos/ignore thresholds match numpy bit-for-bit:
        const float area_a = __fmul_rn(__fsub_rn(ax2, ax1), __fsub_rn(ay2, ay1));

        float best_iou = -1.0f;
        int best = 0;
        #pragma unroll
        for (int j = 0; j < MM; ++j) {
            const float bx1 = ann[j * 5 + 0];
            const float by1 = ann[j * 5 + 1];
            const float bx2 = ann[j * 5 + 2];
            const float by2 = ann[j * 5 + 3];
            const float ix1 = fmaxf(ax1, bx1);
            const float iy1 = fmaxf(ay1, by1);
            const float ix2 = fminf(ax2, bx2);
            const float iy2 = fminf(ay2, by2);
            const float iw = fmaxf(__fsub_rn(ix2, ix1), 0.0f);
            const float ih = fmaxf(__fsub_rn(iy2, iy1), 0.0f);
            const float inter = __fmul_rn(iw, ih);
            const float area_b = __fmul_rn(__fsub_rn(bx2, bx1), __fsub_rn(by2, by1));
            const float uni = __fsub_rn(__fadd_rn(area_a, area_b), inter);
            const float iou = __fdiv_rn(inter, fmaxf(uni, 1e-8f));
            if (iou > best_iou) { best_iou = iou; best = j; }  // strict > keeps first max (argmax)
        }

        const bool pos = best_iou >= 0.5f;
        const bool ign = (best_iou > 0.4f) && !pos;
        const float cx = (ax1 + ax2) * 0.5f;
        const float cy = (ay1 + ay2) * 0.5f;
        const bool inside = (cx >= 0.0f) && (cx < 800.0f) && (cy >= 0.0f) && (cy < 800.0f);

        // code: -2 excluded (state==-1), -1 valid negative, 0..79 positive class
        int code = -2;
        if (inside && !ign) code = pos ? (int)ann[best * 5 + 4] : -1;
        codes[b * AA + a] = (signed char)code;

        if (pos && inside) {                    // state == 1
            pos_cnt = 1;
            const float aw = ax2 - ax1;
            const float ah = ay2 - ay1;
            const float bx1 = ann[best * 5 + 0];
            const float by1 = ann[best * 5 + 1];
            const float bx2 = ann[best * 5 + 2];
            const float by2 = ann[best * 5 + 3];
            float t[4];
            t[0] = ((bx1 - ax1) / aw) / 0.2f;
            t[1] = ((by1 - ay1) / ah) / 0.2f;
            t[2] = ((bx2 - ax2) / aw) / 0.2f;
            t[3] = ((by2 - ay2) / ah) / 0.2f;
            const float* rg = regression + (((size_t)b * AA + a) * 4);
            #pragma unroll
            for (int k = 0; k < 4; ++k) {
                const float d = fabsf(rg[k] - t[k]);
                reg_sum += (d < (1.0f / 9.0f)) ? (4.5f * d * d) : (d - (0.5f / 9.0f));
            }
        }
    }

    #pragma unroll
    for (int off = 32; off > 0; off >>= 1) {
        reg_sum += __shfl_down(reg_sum, off);
        pos_cnt += __shfl_down(pos_cnt, off);
    }
    __shared__ float wr[4];
    __shared__ int   wp[4];
    const int wave = tid >> 6, lane = tid & 63;
    if (lane == 0) { wr[wave] = reg_sum; wp[wave] = pos_cnt; }
    __syncthreads();
    if (tid == 0) {
        const int idx = b * GX + blockIdx.x;
        reg_part[idx] = wr[0] + wr[1] + wr[2] + wr[3];
        pos_part[idx] = (unsigned)(wp[0] + wp[1] + wp[2] + wp[3]);
    }
}

// Flat grid-stride stream over all 8M float4s. Per thread: exactly 10 float4s
// (2 batches of 5). Loads (float4 + code byte) are address-pure (affine in
// tid), issued back-to-back, then sched_barrier(0) pins them above the math —
// the compiler cannot sink them into a load->use serial chain. Validity is a
// post-hoc multiply; the labeled-column term is a rare correction branch.
__global__ __launch_bounds__(256) void focal_kernel(
    const float4* __restrict__ cls4,        // N4
    const signed char* __restrict__ codes,  // BB*AA
    float* __restrict__ cls_part)
{
    const int t0 = blockIdx.x * 256 + threadIdx.x;
    float csum2 = 0.0f;   // sum of p^2 * (-log2(1-p)) over valid elements
    float pcor2 = 0.0f;   // sum of (1-p)^2 * (-log2 p) over labeled elements

    #pragma unroll
    for (int half = 0; half < 2; ++half) {
        float4 v[5];
        int    cd[5];
        #pragma unroll
        for (int k = 0; k < 5; ++k) {
            const int i = t0 + (half * 5 + k) * FT;
            v[k]  = cls4[i];
            cd[k] = codes[i / 20];
        }
        __builtin_amdgcn_sched_barrier(0);   // keep all 10 loads in flight
        #pragma unroll
        for (int k = 0; k < 5; ++k) {
            const int i = t0 + (half * 5 + k) * FT;
            const int s = i / 20;                 // magic-mul
            const int colb = (i - s * 20) * 4;
            const int c = cd[k];

            const float p0 = fminf(fmaxf(v[k].x, 1e-4f), 0.9999f);
            const float p1 = fminf(fmaxf(v[k].y, 1e-4f), 0.9999f);
            const float p2 = fminf(fmaxf(v[k].z, 1e-4f), 0.9999f);
            const float p3 = fminf(fmaxf(v[k].w, 1e-4f), 0.9999f);
            const float l0 = hw_log2(1.0f - p0);  // negative
            const float l1 = hw_log2(1.0f - p1);
            const float l2 = hw_log2(1.0f - p2);
            const float l3 = hw_log2(1.0f - p3);
            float sub = -(p0 * p0 * l0);
            sub -= p1 * p1 * l1;
            sub -= p2 * p2 * l2;
            sub -= p3 * p3 * l3;
            csum2 += (c != -2) ? sub : 0.0f;

            const unsigned rel = (unsigned)(c - colb);
            if (rel < 4u) {                       // rare: labeled column in this float4
                const float p  = (rel & 2u) ? ((rel & 1u) ? p3 : p2) : ((rel & 1u) ? p1 : p0);
                const float ln = (rel & 2u) ? ((rel & 1u) ? l3 : l2) : ((rel & 1u) ? l1 : l0);
                const float onem = 1.0f - p;
                pcor2 -= onem * onem * hw_log2(p);  // add label==1 term
                csum2 += p * p * ln;                // remove label==0 term
            }
        }
    }

    float csum = LN2 * (0.75f * csum2 + 0.25f * pcor2);

    #pragma unroll
    for (int off = 32; off > 0; off >>= 1) csum += __shfl_down(csum, off);
    __shared__ float wc[4];
    const int wave = threadIdx.x >> 6, lane = threadIdx.x & 63;
    if (lane == 0) wc[wave] = csum;
    __syncthreads();
    if (threadIdx.x == 0) cls_part[blockIdx.x] = wc[0] + wc[1] + wc[2] + wc[3];
}

__global__ __launch_bounds__(256) void finalize_kernel(
    const float* __restrict__ reg_part,
    const unsigned* __restrict__ pos_part,
    const float* __restrict__ cls_part,
    float* __restrict__ out)
{
    float cs = 0.0f, rs = 0.0f;
    unsigned pc = 0;
    for (int i = threadIdx.x; i < FB; i += 256) cs += cls_part[i];
    for (int i = threadIdx.x; i < NBLK; i += 256) { rs += reg_part[i]; pc += pos_part[i]; }
    #pragma unroll
    for (int off = 32; off > 0; off >>= 1) {
        cs += __shfl_down(cs, off);
        rs += __shfl_down(rs, off);
        pc += __shfl_down(pc, off);
    }
    __shared__ float wc[4], wr[4];
    __shared__ unsigned wp[4];
    const int wave = threadIdx.x >> 6, lane = threadIdx.x & 63;
    if (lane == 0) { wc[wave] = cs; wr[wave] = rs; wp[wave] = pc; }
    __syncthreads();
    if (threadIdx.x == 0) {
        const float csum = wc[0] + wc[1] + wc[2] + wc[3];
        const float rsum = wr[0] + wr[1] + wr[2] + wr[3];
        const float np = fmaxf((float)(wp[0] + wp[1] + wp[2] + wp[3]), 1.0f);
        out[0] = (csum + rsum) / np;
    }
}

extern "C" void kernel_launch(void* const* d_in, const int* in_sizes, int n_in,
                              void* d_out, int out_size, void* d_ws, size_t ws_size,
                              hipStream_t stream)
{
    const float* classification = (const float*)d_in[0];  // BB*AA*NC
    const float* regression     = (const float*)d_in[1];  // BB*AA*4
    const float* anchors        = (const float*)d_in[2];  // AA*4
    const float* annotations    = (const float*)d_in[3];  // BB*MM*5
    float* out = (float*)d_out;

    float*       reg_part = (float*)d_ws;
    unsigned*    pos_part = (unsigned*)d_ws + NBLK;
    float*       cls_part = (float*)d_ws + 2 * NBLK;
    signed char* codes    = (signed char*)d_ws + 65536;

    dim3 gA(GX, BB);
    codes_kernel<<<gA, 256, 0, stream>>>(anchors, annotations, regression,
                                         reg_part, pos_part, codes);
    focal_kernel<<<FB, 256, 0, stream>>>((const float4*)classification, codes, cls_part);
    finalize_kernel<<<1, 256, 0, stream>>>(reg_part, pos_part, cls_part, out);
}